// Round 1
// baseline (135.134 us; speedup 1.0000x reference)
//
#include <hip/hip_runtime.h>
#include <math.h>

#define GRIDSZ 32
#define GRID3 (GRIDSZ * GRIDSZ * GRIDSZ)
#define BLK 256

// ---------------------------------------------------------------------------
// Scalar output must be zeroed each launch (harness poisons d_out to 0xAA).
// ---------------------------------------------------------------------------
__global__ void zero_out_kernel(float* out) { out[0] = 0.0f; }

struct BatchConst {
    float nv[3][3];      // plane normals
    float pd[3];         // plane d
    float inv_nn[3];     // 1 / |nv|^2
    float Rw[3];         // quat scalar parts
    float Rv[3][3];      // quat vector parts
    float inv_n[3];      // 1 / |R|
};

__device__ __forceinline__ float dist_to_closest(const float* __restrict__ cl,
                                                 float sx, float sy, float sz) {
    // idx3 = floor(clip(sym, 0, 31)); clip first => truncation == floor
    float cx = fminf(fmaxf(sx, 0.0f), 31.0f);
    float cy = fminf(fmaxf(sy, 0.0f), 31.0f);
    float cz = fminf(fmaxf(sz, 0.0f), 31.0f);
    int ix = (int)cx;
    int iy = (int)cy;
    int iz = (int)cz;
    int flat = (ix * GRIDSZ + iy) * GRIDSZ + iz;
    const float* c = cl + (size_t)flat * 3;
    float dx = sx - c[0];
    float dy = sy - c[1];
    float dz = sz - c[2];
    return sqrtf(dx * dx + dy * dy + dz * dz);
}

__global__ __launch_bounds__(BLK) void sym_loss_kernel(
    const float* __restrict__ output,   // (B, 6, 4)
    const float* __restrict__ points,   // (B, N, 3)
    const float* __restrict__ closest,  // (B, G, 3)
    float* __restrict__ out,
    int N, float scale) {
    __shared__ BatchConst bc;
    __shared__ float pts[BLK * 3];
    __shared__ float wave_part[BLK / 64];

    const int b = blockIdx.y;
    const int tid = threadIdx.x;

    if (tid == 0) {
        const float* o = output + (size_t)b * 24;
        #pragma unroll
        for (int r = 0; r < 3; ++r) {
            float nx = o[r * 4 + 0], ny = o[r * 4 + 1], nz = o[r * 4 + 2];
            bc.nv[r][0] = nx; bc.nv[r][1] = ny; bc.nv[r][2] = nz;
            bc.pd[r] = o[r * 4 + 3];
            bc.inv_nn[r] = 1.0f / (nx * nx + ny * ny + nz * nz);
            float rw = o[12 + r * 4 + 0];
            float rx = o[12 + r * 4 + 1];
            float ry = o[12 + r * 4 + 2];
            float rz = o[12 + r * 4 + 3];
            bc.Rw[r] = rw;
            bc.Rv[r][0] = rx; bc.Rv[r][1] = ry; bc.Rv[r][2] = rz;
            bc.inv_n[r] = rsqrtf(rw * rw + rx * rx + ry * ry + rz * rz);
        }
    }

    // Stage this block's 256 points (768 floats) into LDS, coalesced.
    const int n0 = blockIdx.x * BLK;
    const float* psrc = points + ((size_t)b * N + n0) * 3;
    pts[tid]           = psrc[tid];
    pts[tid + BLK]     = psrc[tid + BLK];
    pts[tid + 2 * BLK] = psrc[tid + 2 * BLK];
    __syncthreads();

    const float px = pts[tid * 3 + 0];
    const float py = pts[tid * 3 + 1];
    const float pz = pts[tid * 3 + 2];
    const float* cl = closest + (size_t)b * GRID3 * 3;

    float acc = 0.0f;

    // 3 plane reflections
    #pragma unroll
    for (int r = 0; r < 3; ++r) {
        float nx = bc.nv[r][0], ny = bc.nv[r][1], nz = bc.nv[r][2];
        float dis = (nx * px + ny * py + nz * pz + bc.pd[r]) * bc.inv_nn[r];
        float sx = px - 2.0f * dis * nx;
        float sy = py - 2.0f * dis * ny;
        float sz = pz - 2.0f * dis * nz;
        acc += dist_to_closest(cl, sx, sy, sz);
    }

    // 3 quaternion rotations: rot = (R * (0,p) * conj(R)/|R|).vec
    //   w1 = -Rv.p ; v1 = Rw*p + Rv x p ; rot = (Rw*v1 - w1*Rv + Rv x v1)/|R|
    #pragma unroll
    for (int r = 0; r < 3; ++r) {
        float rw = bc.Rw[r];
        float rx = bc.Rv[r][0], ry = bc.Rv[r][1], rz = bc.Rv[r][2];
        float inv_n = bc.inv_n[r];

        float w1 = -(rx * px + ry * py + rz * pz);
        float v1x = rw * px + (ry * pz - rz * py);
        float v1y = rw * py + (rz * px - rx * pz);
        float v1z = rw * pz + (rx * py - ry * px);

        float sx = (rw * v1x - w1 * rx + (ry * v1z - rz * v1y)) * inv_n;
        float sy = (rw * v1y - w1 * ry + (rz * v1x - rx * v1z)) * inv_n;
        float sz = (rw * v1z - w1 * rz + (rx * v1y - ry * v1x)) * inv_n;
        acc += dist_to_closest(cl, sx, sy, sz);
    }

    // Wave-64 shuffle reduction, then cross-wave via LDS, one atomic per block.
    #pragma unroll
    for (int off = 32; off > 0; off >>= 1)
        acc += __shfl_down(acc, off, 64);

    const int wave = tid >> 6;
    const int lane = tid & 63;
    if (lane == 0) wave_part[wave] = acc;
    __syncthreads();

    if (tid == 0) {
        float total = 0.0f;
        #pragma unroll
        for (int w = 0; w < BLK / 64; ++w) total += wave_part[w];
        atomicAdd(out, total * scale);
    }
}

extern "C" void kernel_launch(void* const* d_in, const int* in_sizes, int n_in,
                              void* d_out, int out_size, void* d_ws, size_t ws_size,
                              hipStream_t stream) {
    const float* output  = (const float*)d_in[0];   // (B, 6, 4)
    const float* points  = (const float*)d_in[1];   // (B, N, 3)
    const float* closest = (const float*)d_in[2];   // (B, G, 3)
    float* out = (float*)d_out;

    const int B = in_sizes[0] / 24;                 // 64
    const int N = in_sizes[1] / (B * 3);            // 16384
    const float scale = 1.0f / ((float)B * (float)N);

    zero_out_kernel<<<1, 1, 0, stream>>>(out);

    dim3 grid(N / BLK, B);
    sym_loss_kernel<<<grid, BLK, 0, stream>>>(output, points, closest, out, N, scale);
}